// Round 6
// baseline (32.119 us; speedup 1.0000x reference)
//
#include <hip/hip_runtime.h>

#define POOL 7
#define FM_H 128
#define FM_W 128
#define FM_C 512
#define NGRP 8                 // channel groups == XCD count; 64 ch = 4 MiB slice
#define CELLS_PER_BLK 16       // 256 threads = 16 cells x 16 lanes x float4

typedef float f32x4 __attribute__((ext_vector_type(4)));

// Kernel 1: sequential L2 warm. Each XCD streams its own 4 MiB channel slice
// (group g = blockIdx&7 -> XCD g) into L2 in pixel order, converting the
// otherwise ROI-random HBM read stream of kernel 2 into one sequential sweep.
__global__ __launch_bounds__(256) void prefetch_kernel(
    const float* __restrict__ fm)
{
    const int g = blockIdx.x & 7;           // channel group -> XCD
    const int b = blockIdx.x >> 3;          // 0..511 per group
    const int t = threadIdx.x;
    const int pix = (b << 5) + (t >> 3);    // 32 pixels/block, 16384 total
    const size_t base = (size_t)pix * FM_C + (g << 6) + ((t & 7) << 2);

    const f32x4 a = *reinterpret_cast<const f32x4*>(fm + base);
    const f32x4 c = *reinterpret_cast<const f32x4*>(fm + base + 32); // +128 B

    // Keep the loads alive (prevent DCE) without any store traffic.
    asm volatile("" :: "v"(a.x), "v"(a.y), "v"(a.z), "v"(a.w),
                       "v"(c.x), "v"(c.y), "v"(c.z), "v"(c.w));
}

// Kernel 2: R4 structure (proven 27.5us). Channel-partitioned, XCD-pinned;
// corner reads should now hit the L2 warmed by prefetch_kernel.
__global__ __launch_bounds__(256) void roi_pool_kernel(
    const float* __restrict__ fm,    // [128,128,512] NHWC (batch 1)
    const float* __restrict__ rois,  // [R,4] = xmin,xmax,ymin,ymax (integral floats)
    float* __restrict__ out,         // [R,7,7,512]
    int n_cells)                     // R*49
{
    const int tid  = threadIdx.x;
    const int g    = blockIdx.x & (NGRP - 1);        // channel group -> XCD
    const int cb   = blockIdx.x >> 3;
    const int cell = cb * CELLS_PER_BLK + (tid >> 4);
    if (cell >= n_cells) return;
    const int c4   = (g << 6) + ((tid & 15) << 2);   // g*64 + lane16*4

    const int r  = cell / (POOL * POOL);
    const int p  = cell - r * (POOL * POOL);
    const int py = p / POOL;
    const int px = p - py * POOL;

    // rois are integral values stored as f32; astype(int32) == truncation.
    const float4 rv = *reinterpret_cast<const float4*>(rois + (size_t)r * 4);
    const int xmin = (int)rv.x;
    const int xmax = (int)rv.y;
    const int ymin = (int)rv.z;
    const int ymax = (int)rv.w;
    const int sy = ymax - ymin;
    const int sx = xmax - xmin;

    // _axis_coords, replicated op-for-op in fp32 to match the reference.
    const float scy  = (float)sy / 7.0f;
    const float srcy = (float)py * scy;
    const int   iy0  = (int)floorf(srcy);
    const int   iy1  = min(iy0 + 1, sy - 1);
    const float fy   = srcy - (float)iy0;
    const int   y0   = ymin + iy0;
    const int   y1   = ymin + iy1;

    const float scx  = (float)sx / 7.0f;
    const float srcx = (float)px * scx;
    const int   ix0  = (int)floorf(srcx);
    const int   ix1  = min(ix0 + 1, sx - 1);
    const float fx   = srcx - (float)ix0;
    const int   x0   = xmin + ix0;
    const int   x1   = xmin + ix1;

    const size_t o00 = ((size_t)(y0 * FM_W + x0)) * FM_C + c4;
    const size_t o01 = ((size_t)(y0 * FM_W + x1)) * FM_C + c4;
    const size_t o10 = ((size_t)(y1 * FM_W + x0)) * FM_C + c4;
    const size_t o11 = ((size_t)(y1 * FM_W + x1)) * FM_C + c4;

    const float4 tl = *reinterpret_cast<const float4*>(fm + o00);
    const float4 tr = *reinterpret_cast<const float4*>(fm + o01);
    const float4 bl = *reinterpret_cast<const float4*>(fm + o10);
    const float4 br = *reinterpret_cast<const float4*>(fm + o11);

    f32x4 o;
    {
        float top, bot;
        top = tl.x + (tr.x - tl.x) * fx; bot = bl.x + (br.x - bl.x) * fx; o.x = top + (bot - top) * fy;
        top = tl.y + (tr.y - tl.y) * fx; bot = bl.y + (br.y - bl.y) * fx; o.y = top + (bot - top) * fy;
        top = tl.z + (tr.z - tl.z) * fx; bot = bl.z + (br.z - bl.z) * fx; o.z = top + (bot - top) * fy;
        top = tl.w + (tr.w - tl.w) * fx; bot = bl.w + (br.w - bl.w) * fx; o.w = top + (bot - top) * fy;
    }

    // Nontemporal streaming store — keep the write-once output from evicting
    // the warmed fm slice.
    f32x4* dst = reinterpret_cast<f32x4*>(out + (size_t)cell * FM_C + c4);
    __builtin_nontemporal_store(o, dst);
}

extern "C" void kernel_launch(void* const* d_in, const int* in_sizes, int n_in,
                              void* d_out, int out_size, void* d_ws, size_t ws_size,
                              hipStream_t stream) {
    const float* fm   = (const float*)d_in[0];
    const float* rois = (const float*)d_in[1];
    float* out        = (float*)d_out;

    const int R       = in_sizes[1] / 4;
    const int n_cells = R * POOL * POOL;                                // 50176
    const int cblocks = (n_cells + CELLS_PER_BLK - 1) / CELLS_PER_BLK;  // 3136
    const int blocks  = cblocks * NGRP;                                 // 25088

    // 16384 pixels / 32 per block = 512 blocks per group x 8 groups.
    prefetch_kernel<<<512 * NGRP, 256, 0, stream>>>(fm);
    roi_pool_kernel<<<blocks, 256, 0, stream>>>(fm, rois, out, n_cells);
}

// Round 7
// 28.635 us; speedup vs baseline: 1.1217x; 1.1217x over previous
//
#include <hip/hip_runtime.h>

#define POOL 7
#define FM_H 128
#define FM_W 128
#define FM_C 512
#define NGRP 8                  // channel groups == XCD count; 64 ch = 4 MiB slice
#define CELLS_PER_ITER 16       // 256 threads = 16 cells x 16 lanes x float4
#define BLOCKS_PER_GRP 256      // 2048 blocks total = 8/CU -> full residency

typedef float f32x4 __attribute__((ext_vector_type(4)));

// Persistent grid-stride ROI pooling, channel-partitioned + XCD-pinned.
// R4 proved channel->XCD pinning (60->27.5us). R6 proved reads are L2-hot and
// k2 is overlap-limited, not HBM-read-limited -> switch to 2048 persistent
// blocks (full 32-wave/CU residency) with unroll-2 grid-stride loop for ILP.
__global__ __launch_bounds__(256) void roi_pool_kernel(
    const float* __restrict__ fm,    // [128,128,512] NHWC (batch 1)
    const float* __restrict__ rois,  // [R,4] = xmin,xmax,ymin,ymax (integral floats)
    float* __restrict__ out,         // [R,7,7,512]
    int n_cells)                     // R*49
{
    const int tid = threadIdx.x;
    const int g   = blockIdx.x & (NGRP - 1);         // channel group -> XCD
    const int bb  = blockIdx.x >> 3;                 // 0..BLOCKS_PER_GRP-1
    const int c4  = (g << 6) + ((tid & 15) << 2);    // g*64 + lane16*4
    const int ci  = tid >> 4;                        // cell-in-block 0..15

    const int stride = BLOCKS_PER_GRP * CELLS_PER_ITER;  // 4096 cells/sweep

    #pragma unroll 2
    for (int cell = bb * CELLS_PER_ITER + ci; cell < n_cells; cell += stride) {
        const int r  = cell / (POOL * POOL);
        const int p  = cell - r * (POOL * POOL);
        const int py = p / POOL;
        const int px = p - py * POOL;

        // rois are integral values stored as f32; astype(int32) == truncation.
        const float4 rv = *reinterpret_cast<const float4*>(rois + (size_t)r * 4);
        const int xmin = (int)rv.x;
        const int xmax = (int)rv.y;
        const int ymin = (int)rv.z;
        const int ymax = (int)rv.w;
        const int sy = ymax - ymin;
        const int sx = xmax - xmin;

        // _axis_coords, replicated op-for-op in fp32 to match the reference.
        const float scy  = (float)sy / 7.0f;
        const float srcy = (float)py * scy;
        const int   iy0  = (int)floorf(srcy);
        const int   iy1  = min(iy0 + 1, sy - 1);
        const float fy   = srcy - (float)iy0;
        const int   y0   = ymin + iy0;
        const int   y1   = ymin + iy1;

        const float scx  = (float)sx / 7.0f;
        const float srcx = (float)px * scx;
        const int   ix0  = (int)floorf(srcx);
        const int   ix1  = min(ix0 + 1, sx - 1);
        const float fx   = srcx - (float)ix0;
        const int   x0   = xmin + ix0;
        const int   x1   = xmin + ix1;

        const size_t o00 = ((size_t)(y0 * FM_W + x0)) * FM_C + c4;
        const size_t o01 = ((size_t)(y0 * FM_W + x1)) * FM_C + c4;
        const size_t o10 = ((size_t)(y1 * FM_W + x0)) * FM_C + c4;
        const size_t o11 = ((size_t)(y1 * FM_W + x1)) * FM_C + c4;

        const float4 tl = *reinterpret_cast<const float4*>(fm + o00);
        const float4 tr = *reinterpret_cast<const float4*>(fm + o01);
        const float4 bl = *reinterpret_cast<const float4*>(fm + o10);
        const float4 br = *reinterpret_cast<const float4*>(fm + o11);

        f32x4 o;
        {
            float top, bot;
            top = tl.x + (tr.x - tl.x) * fx; bot = bl.x + (br.x - bl.x) * fx; o.x = top + (bot - top) * fy;
            top = tl.y + (tr.y - tl.y) * fx; bot = bl.y + (br.y - bl.y) * fx; o.y = top + (bot - top) * fy;
            top = tl.z + (tr.z - tl.z) * fx; bot = bl.z + (br.z - bl.z) * fx; o.z = top + (bot - top) * fy;
            top = tl.w + (tr.w - tl.w) * fx; bot = bl.w + (br.w - bl.w) * fx; o.w = top + (bot - top) * fy;
        }

        // Nontemporal streaming store — keep the write-once output out of L2.
        f32x4* dst = reinterpret_cast<f32x4*>(out + (size_t)cell * FM_C + c4);
        __builtin_nontemporal_store(o, dst);
    }
}

extern "C" void kernel_launch(void* const* d_in, const int* in_sizes, int n_in,
                              void* d_out, int out_size, void* d_ws, size_t ws_size,
                              hipStream_t stream) {
    const float* fm   = (const float*)d_in[0];
    const float* rois = (const float*)d_in[1];
    float* out        = (float*)d_out;

    const int R       = in_sizes[1] / 4;
    const int n_cells = R * POOL * POOL;          // 50176
    const int blocks  = BLOCKS_PER_GRP * NGRP;    // 2048

    roi_pool_kernel<<<blocks, 256, 0, stream>>>(fm, rois, out, n_cells);
}